// Round 5
// baseline (213.374 us; speedup 1.0000x reference)
//
#include <hip/hip_runtime.h>

#define T_LEN 1024
#define NH 8
#define DH 64
#define CCH 512
#define LOG2E 1.44269504088896340736f

typedef _Float16 f16;
typedef _Float16 f16x8 __attribute__((ext_vector_type(8)));
typedef _Float16 f16x4 __attribute__((ext_vector_type(4)));
typedef float f32x4 __attribute__((ext_vector_type(4)));

// async global->LDS DMA, 16B per lane. LDS dest must equal wave-uniform base + lane*16.
__device__ __forceinline__ void dma16(const void* g, void* l)
{
    __builtin_amdgcn_global_load_lds((const __attribute__((address_space(1))) void*)g,
                                     (__attribute__((address_space(3))) void*)l, 16, 0, 0);
}

// ---------------------------------------------------------------------------
// prep: fused [transpose+cvt x -> xT fp16 [b*t][c]] and [W fp32 -> fp16].
// grid(16, 8, 3B + 8), block 256.  (unchanged)
// ---------------------------------------------------------------------------
__global__ __launch_bounds__(256)
void prep_kernel(const float* __restrict__ x0, const float* __restrict__ x1,
                 const float* __restrict__ x2, const float* __restrict__ W0,
                 const float* __restrict__ W1, const float* __restrict__ W2,
                 const float* __restrict__ W3, f16* __restrict__ o0,
                 f16* __restrict__ o1, f16* __restrict__ o2, f16* __restrict__ w0,
                 f16* __restrict__ w1, f16* __restrict__ w2, f16* __restrict__ w3,
                 int B)
{
    const int z = blockIdx.z;
    if (z < 3 * B) {
        const int t0 = blockIdx.x * 64, c0 = blockIdx.y * 64;
        const int which = z / B, b = z % B;
        const float* x = (which == 0) ? x0 : (which == 1) ? x1 : x2;
        f16* o = (which == 0) ? o0 : (which == 1) ? o1 : o2;

        __shared__ float L[64 * 68];
        const int cl = threadIdx.x & 63, g = threadIdx.x >> 6;
        const float* src = x + ((size_t)(b * CCH + c0 + cl)) * T_LEN + t0 + g * 16;
        #pragma unroll
        for (int j = 0; j < 4; ++j)
            *(float4*)&L[cl * 68 + g * 16 + 4 * j] = *(const float4*)&src[4 * j];
        __syncthreads();
        const int tl = threadIdx.x & 63, cg = (threadIdx.x >> 6) * 16;
        f16 h[16];
        #pragma unroll
        for (int j = 0; j < 16; ++j) h[j] = (f16)L[(cg + j) * 68 + tl];
        f16* dst = o + ((size_t)(b * T_LEN + t0 + tl)) * CCH + c0 + cg;
        *(f16x8*)&dst[0] = *(f16x8*)&h[0];
        *(f16x8*)&dst[8] = *(f16x8*)&h[8];
    } else {
        const int slice = z - 3 * B;
        size_t i = ((size_t)(slice * 128 + blockIdx.y * 16 + blockIdx.x) * 256 + threadIdx.x) * 4;
        const int wi = (int)(i >> 18);
        const size_t off = i & 262143;
        const float* src = (wi == 0) ? W0 : (wi == 1) ? W1 : (wi == 2) ? W2 : W3;
        f16* dst = (wi == 0) ? w0 : (wi == 1) ? w1 : (wi == 2) ? w2 : w3;
        float4 v4 = *(const float4*)&src[off];
        f16x4 h = {(f16)v4.x, (f16)v4.y, (f16)v4.z, (f16)v4.w};
        *(f16x4*)&dst[off] = h;
    }
}

// ---------------------------------------------------------------------------
// Fused q/k/v projections: X fragments DIRECT from global (read-once);
// W (read 4x/block) in double-buffered LDS via DMA. 128(t)x64(o) tile, BK=64.
// grid(B*8, 8, 3), block 256.
// ---------------------------------------------------------------------------
__global__ __launch_bounds__(256)
void proj_qkv(const f16* __restrict__ xq, const f16* __restrict__ xk,
              const f16* __restrict__ xv, const f16* __restrict__ wq,
              const f16* __restrict__ wk, const f16* __restrict__ wv,
              const float* __restrict__ bq, const float* __restrict__ bk,
              const float* __restrict__ bv, f16* __restrict__ qo,
              f16* __restrict__ ko, f16* __restrict__ vo)
{
    const int which = blockIdx.z;
    const f16* X = (which == 0) ? xq : (which == 1) ? xk : xv;
    const f16* W = (which == 0) ? wq : (which == 1) ? wk : wv;
    const float* bias = (which == 0) ? bq : (which == 1) ? bk : bv;
    const float scale = (which == 0) ? 0.125f * LOG2E : 1.0f;

    const int r0 = blockIdx.x * 128;
    const int o0 = blockIdx.y * 64;
    const int tid = threadIdx.x;
    const int w = tid >> 6, lane = tid & 63;
    const int quad = lane >> 4, l15 = lane & 15;

    __shared__ __align__(16) f16 Ws[2][64 * 64];

    const int srow = tid >> 3;
    const int scol = ((tid & 7) ^ (srow & 7)) << 3;
    const f16* Wg = W + (size_t)(o0 + srow) * CCH + scol;

    // per-lane direct X fragment base: row = r0+32w+16im+l15, k = kc*64+ks*32+quad*8
    const f16* xp = X + (size_t)(r0 + 32 * w + l15) * CCH + quad * 8;

    #pragma unroll
    for (int j = 0; j < 2; ++j)
        dma16(Wg + (size_t)(32 * j) * CCH, &Ws[0][(size_t)tid * 8 + j * 2048]);

    f32x4 acc[8] = {};

    for (int kc = 0; kc < 8; ++kc) {
        __syncthreads();   // drains W DMA for chunk kc
        if (kc < 7) {
            const int bf = (kc + 1) & 1, c1 = (kc + 1) * 64;
            #pragma unroll
            for (int j = 0; j < 2; ++j)
                dma16(Wg + c1 + (size_t)(32 * j) * CCH, &Ws[bf][(size_t)tid * 8 + j * 2048]);
        }
        const int cb = kc & 1;
        #pragma unroll
        for (int ks = 0; ks < 2; ++ks) {
            const int sl = ((ks * 4 + quad) ^ (l15 & 7)) << 3;
            f16x8 xf[2], wf[4];
            #pragma unroll
            for (int im = 0; im < 2; ++im)
                xf[im] = *(const f16x8*)&xp[(size_t)(16 * im) * CCH + kc * 64 + ks * 32];
            #pragma unroll
            for (int cm = 0; cm < 4; ++cm)
                wf[cm] = *(const f16x8*)&Ws[cb][(16 * cm + l15) * 64 + sl];
            if (which < 2) {
                #pragma unroll
                for (int im = 0; im < 2; ++im)
                    #pragma unroll
                    for (int cm = 0; cm < 4; ++cm)
                        acc[im * 4 + cm] = __builtin_amdgcn_mfma_f32_16x16x32_f16(
                            xf[im], wf[cm], acc[im * 4 + cm], 0, 0, 0);
            } else {
                #pragma unroll
                for (int cm = 0; cm < 4; ++cm)
                    #pragma unroll
                    for (int in = 0; in < 2; ++in)
                        acc[cm * 2 + in] = __builtin_amdgcn_mfma_f32_16x16x32_f16(
                            wf[cm], xf[in], acc[cm * 2 + in], 0, 0, 0);
            }
        }
    }

    if (which < 2) {
        f16* out = (which == 0) ? qo : ko;
        float bl[4];
        #pragma unroll
        for (int cm = 0; cm < 4; ++cm) bl[cm] = bias[o0 + 16 * cm + l15];
        #pragma unroll
        for (int im = 0; im < 2; ++im)
            #pragma unroll
            for (int r = 0; r < 4; ++r) {
                size_t row = (size_t)(r0 + 32 * w + 16 * im + 4 * quad + r) * CCH;
                #pragma unroll
                for (int cm = 0; cm < 4; ++cm)
                    out[row + o0 + 16 * cm + l15] =
                        (f16)((acc[im * 4 + cm][r] + bl[cm]) * scale);
            }
    } else {
        const int bb = r0 >> 10, tb = r0 & 1023;
        #pragma unroll
        for (int cm = 0; cm < 4; ++cm) {
            float4 bv4 = *(const float4*)&bias[o0 + 16 * cm + 4 * quad];
            float bl[4] = {bv4.x, bv4.y, bv4.z, bv4.w};
            #pragma unroll
            for (int r = 0; r < 4; ++r) {
                size_t row = ((size_t)(bb * CCH + o0 + 16 * cm + 4 * quad + r)) * T_LEN;
                #pragma unroll
                for (int in = 0; in < 2; ++in)
                    vo[row + tb + 32 * w + 16 * in + l15] =
                        (f16)(acc[cm * 2 + in][r] + bl[r]);
            }
        }
    }
}

// ---------------------------------------------------------------------------
// MFMA flash attention v3: K and V fragments DIRECT from global (L1-served,
// all 4 waves read identical addresses); only Q (corner bias) and P (C->A
// transpose) in LDS. 2 barriers/iter, no staging DMA in the loop.
// grid(16, NH, 2B), block 256. Split-K(2), no-max softmax, S^T orientation.
// ---------------------------------------------------------------------------
__global__ __launch_bounds__(256)
void attn_mfma(const f16* __restrict__ q, const f16* __restrict__ kk,
               const f16* __restrict__ v, const float* __restrict__ ekg,
               const float* __restrict__ evg, f16* __restrict__ Op0,
               f16* __restrict__ Op1, float* __restrict__ l0,
               float* __restrict__ l1)
{
    const int t0 = blockIdx.x * 64, h = blockIdx.y;
    const int b = blockIdx.z >> 1, split = blockIdx.z & 1;
    const int tid = threadIdx.x;
    const int w = tid >> 6, lane = tid & 63;
    const int quad = lane >> 4, l15 = lane & 15;

    f16* Op = split ? Op1 : Op0;
    float* lbuf = split ? l1 : l0;

    __shared__ __align__(16) f16 Qs[4096], Ps[4096];
    __shared__ float eks[576], evs[576];

    const int srow = tid >> 3;
    const int scol = ((tid & 7) ^ (srow & 7)) << 3;

    for (int i = tid; i < 576; i += 256) {
        eks[i] = ekg[h * 576 + i];
        evs[i] = evg[h * 576 + i];
    }

    dma16(q + ((size_t)(b * T_LEN + t0 + srow)) * CCH + h * DH + scol, &Qs[(size_t)tid * 8]);
    dma16(q + ((size_t)(b * T_LEN + t0 + srow + 32)) * CCH + h * DH + scol, &Qs[((size_t)tid + 256) * 8]);
    __syncthreads();

    f16x8 qf[2];
    #pragma unroll
    for (int ks = 0; ks < 2; ++ks)
        qf[ks] = *(const f16x8*)&Qs[(16 * w + l15) * 64 + (((ks * 4 + quad) ^ (l15 & 7)) << 3)];

    const int kb0 = split * 8;
    // per-lane direct fragment bases:
    // K A-frag: row s = s0+16ct+l15, k = ks*32+quad*8  (k-tensor [b*t][c])
    const f16* kp = kk + ((size_t)(b * T_LEN + kb0 * 64 + l15)) * CCH + h * DH + quad * 8;
    // V B-frag: row d = 16ct+l15, k = s0+ks*32+quad*8  (v-tensor [b][c][t])
    const f16* vp = v + ((size_t)(b * CCH + h * DH + l15)) * T_LEN + kb0 * 64 + quad * 8;

    const int myt = 16 * w + l15;
    float Ssum = 0.f;
    f32x4 O[4] = {};

    const bool corner_hi = (blockIdx.x == 0) && (split == 1);
    const bool corner_lo = (blockIdx.x == 15) && (split == 0);

    for (int kb = kb0; kb < kb0 + 8; ++kb) {
        const int ko = (kb - kb0) * 64;

        // ----- S^T = K Q^T, K direct from global -----
        f32x4 S[4] = {};
        #pragma unroll
        for (int ks = 0; ks < 2; ++ks) {
            f16x8 kf[4];
            #pragma unroll
            for (int ct = 0; ct < 4; ++ct)
                kf[ct] = *(const f16x8*)&kp[(size_t)(ko + 16 * ct) * CCH + ks * 32];
            #pragma unroll
            for (int ct = 0; ct < 4; ++ct)
                S[ct] = __builtin_amdgcn_mfma_f32_16x16x32_f16(kf[ct], qf[ks], S[ct], 0, 0, 0);
        }

        // ----- corner relative-K bias (rare) -----
        if ((corner_hi && kb == 15) || (corner_lo && kb == 0)) {
            const int s0g = kb * 64;
            #pragma unroll
            for (int ct = 0; ct < 4; ++ct)
                #pragma unroll
                for (int r = 0; r < 4; ++r) {
                    int t_g = t0 + myt;
                    int s_g = s0g + 16 * ct + 4 * quad + r;
                    int df = s_g - t_g;
                    if (df >= 1019 && df <= 1023) {
                        const float* ekp = &eks[(df - 1019) * 64];
                        float sacc = 0.f;
                        for (int d = 0; d < 64; ++d)
                            sacc += (float)Qs[myt * 64 + (((d >> 3) ^ (myt & 7)) << 3) + (d & 7)] * ekp[d];
                        S[ct][r] += sacc;
                    } else if (df >= -1023 && df <= -1021) {
                        const float* ekp = &eks[(1029 + df) * 64];
                        const int t2 = myt - 1;
                        float sacc = 0.f;
                        for (int d = 0; d < 64; ++d)
                            sacc += (float)Qs[t2 * 64 + (((d >> 3) ^ (t2 & 7)) << 3) + (d & 7)] * ekp[d];
                        S[ct][r] += sacc;
                    }
                }
        }

        // ----- no-max softmax: P = exp2(S) -----
        f16x4 pk_[4];
        #pragma unroll
        for (int ct = 0; ct < 4; ++ct)
            #pragma unroll
            for (int r = 0; r < 4; ++r) {
                float p = exp2f(S[ct][r]);
                Ssum += p;
                pk_[ct][r] = (f16)p;
            }

        __syncthreads();   // (B) all waves done reading Ps of previous iter
        #pragma unroll
        for (int ct = 0; ct < 4; ++ct) {
            int colh = (((2 * ct + (quad >> 1)) ^ (myt & 7)) << 3) + (quad & 1) * 4;
            *(f16x4*)&Ps[myt * 64 + colh] = pk_[ct];
        }
        __syncthreads();   // (A) Ps visible

        // ----- O += P V, V direct from global -----
        #pragma unroll
        for (int ks = 0; ks < 2; ++ks) {
            f16x8 a = *(const f16x8*)&Ps[(16 * w + l15) * 64 + (((ks * 4 + quad) ^ (l15 & 7)) << 3)];
            f16x8 vf[4];
            #pragma unroll
            for (int ct = 0; ct < 4; ++ct)
                vf[ct] = *(const f16x8*)&vp[(size_t)(16 * ct) * T_LEN + ko + ks * 32];
            #pragma unroll
            for (int ct = 0; ct < 4; ++ct)
                O[ct] = __builtin_amdgcn_mfma_f32_16x16x32_f16(a, vf[ct], O[ct], 0, 0, 0);
        }

        // ----- windowed relative-V -----
        const int s0g = kb * 64;
        if (s0g <= t0 + 67 && s0g + 63 >= t0 - 4) {
            #pragma unroll
            for (int r = 0; r < 4; ++r) {
                int t_loc = 16 * w + 4 * quad + r;
                int t_g = t0 + t_loc;
                int slo = max(s0g, t_g - 4), shi = min(s0g + 63, t_g + 4);
                for (int s = slo; s <= shi; ++s) {
                    int sl = s - s0g;
                    float p = (float)Ps[t_loc * 64 + (((sl >> 3) ^ (t_loc & 7)) << 3) + (sl & 7)];
                    const float* evp = &evs[(s - t_g + 4) * 64];
                    #pragma unroll
                    for (int ct = 0; ct < 4; ++ct)
                        O[ct][r] += p * evp[16 * ct + l15];
                }
            }
        }
    }

    Ssum += __shfl_xor(Ssum, 16);
    Ssum += __shfl_xor(Ssum, 32);
    if (quad == 0)
        lbuf[((size_t)b * NH + h) * T_LEN + t0 + myt] = Ssum;

    #pragma unroll
    for (int r = 0; r < 4; ++r) {
        int t_g = t0 + 16 * w + 4 * quad + r;
        size_t rowo = ((size_t)(b * T_LEN + t_g)) * CCH + h * DH;
        #pragma unroll
        for (int ct = 0; ct < 4; ++ct)
            Op[rowo + 16 * ct + l15] = (f16)O[ct][r];
    }
}

// ---------------------------------------------------------------------------
// Split-combine: ctx = (Op0+Op1)/(l0+l1), f16. grid(B*256), block 256.
// ---------------------------------------------------------------------------
__global__ __launch_bounds__(256)
void combine_kernel(const f16* __restrict__ Op0, const f16* __restrict__ Op1,
                    const float* __restrict__ l0, const float* __restrict__ l1,
                    f16* __restrict__ ctx)
{
    const size_t i8 = ((size_t)blockIdx.x * 256 + threadIdx.x) * 8;
    const size_t gr = i8 >> 9;
    const int h = (int)((i8 & 511) >> 6);
    const size_t li = ((gr >> 10) * NH + h) * T_LEN + (gr & 1023);
    const float rl = 1.0f / (l0[li] + l1[li]);
    f16x8 a0 = *(const f16x8*)&Op0[i8];
    f16x8 a1 = *(const f16x8*)&Op1[i8];
    f16 o[8];
    #pragma unroll
    for (int e = 0; e < 8; ++e)
        o[e] = (f16)(((float)a0[e] + (float)a1[e]) * rl);
    *(f16x8*)&ctx[i8] = *(f16x8*)o;
}

// ---------------------------------------------------------------------------
// Output projection: Wo in LDS (read 4x), ctx fragments DIRECT from global.
// 64(o)x64(t) tile, BK=64, double-buffered W DMA. grid(B*16, 8), block 256.
// D[m=o][n=t], fp32 out [b][o][t].
// ---------------------------------------------------------------------------
__global__ __launch_bounds__(256)
void proj_out(const f16* __restrict__ ctx, const f16* __restrict__ Wo,
              const float* __restrict__ bo, float* __restrict__ out)
{
    const int r0 = blockIdx.x * 64;    // flat (b,t)
    const int o0 = blockIdx.y * 64;
    const int tid = threadIdx.x;
    const int w = tid >> 6, lane = tid & 63;
    const int quad = lane >> 4, l15 = lane & 15;

    __shared__ __align__(16) f16 Ws[2][64 * 64];

    const int srow = tid >> 3;
    const int scol = ((tid & 7) ^ (srow & 7)) << 3;
    const f16* Wg = Wo + (size_t)(o0 + srow) * CCH + scol;

    // direct ctx B-frag base: row t = r0+16w+l15, k = kc*64+ks*32+quad*8
    const f16* cp = ctx + (size_t)(r0 + 16 * w + l15) * CCH + quad * 8;

    #pragma unroll
    for (int j = 0; j < 2; ++j)
        dma16(Wg + (size_t)(32 * j) * CCH, &Ws[0][(size_t)tid * 8 + j * 2048]);

    f32x4 acc[4] = {};

    for (int kc = 0; kc < 8; ++kc) {
        __syncthreads();
        if (kc < 7) {
            const int bf = (kc + 1) & 1, c1 = (kc + 1) * 64;
            #pragma unroll
            for (int j = 0; j < 2; ++j)
                dma16(Wg + c1 + (size_t)(32 * j) * CCH, &Ws[bf][(size_t)tid * 8 + j * 2048]);
        }
        const int cb = kc & 1;
        #pragma unroll
        for (int ks = 0; ks < 2; ++ks) {
            const int sl = ((ks * 4 + quad) ^ (l15 & 7)) << 3;
            f16x8 cf = *(const f16x8*)&cp[kc * 64 + ks * 32];
            #pragma unroll
            for (int cm = 0; cm < 4; ++cm) {
                f16x8 wf = *(const f16x8*)&Ws[cb][(16 * cm + l15) * 64 + sl];
                acc[cm] = __builtin_amdgcn_mfma_f32_16x16x32_f16(wf, cf, acc[cm], 0, 0, 0);
            }
        }
    }

    const int bb = r0 >> 10, tb = r0 & 1023;
    #pragma unroll
    for (int cm = 0; cm < 4; ++cm) {
        float4 bv4 = *(const float4*)&bo[o0 + 16 * cm + 4 * quad];
        float bl[4] = {bv4.x, bv4.y, bv4.z, bv4.w};
        #pragma unroll
        for (int r = 0; r < 4; ++r) {
            size_t row = ((size_t)(bb * CCH + o0 + 16 * cm + 4 * quad + r)) * T_LEN;
            out[row + tb + 16 * w + l15] = acc[cm][r] + bl[r];
        }
    }
}

// ---------------------------------------------------------------------------
extern "C" void kernel_launch(void* const* d_in, const int* in_sizes, int n_in,
                              void* d_out, int out_size, void* d_ws, size_t ws_size,
                              hipStream_t stream)
{
    const float* x_q = (const float*)d_in[0];
    const float* x_k = (const float*)d_in[1];
    const float* x_v = (const float*)d_in[2];
    const float* Wq  = (const float*)d_in[3];
    const float* bq  = (const float*)d_in[4];
    const float* Wk  = (const float*)d_in[5];
    const float* bk  = (const float*)d_in[6];
    const float* Wv  = (const float*)d_in[7];
    const float* bv  = (const float*)d_in[8];
    const float* Wo  = (const float*)d_in[9];
    const float* bo  = (const float*)d_in[10];
    const float* erk = (const float*)d_in[11];
    const float* erv = (const float*)d_in[12];

    const int B = in_sizes[0] / (CCH * T_LEN);
    const size_t te = (size_t)B * CCH * T_LEN;
    const size_t we = (size_t)CCH * CCH;

    f16* p = (f16*)d_ws;
    f16* xTq = p; p += te;
    f16* xTk = p; p += te;
    f16* xTv = p; p += te;
    f16* wqh = p; p += we;
    f16* wkh = p; p += we;
    f16* wvh = p; p += we;
    f16* woh = p; p += we;
    f16* qh  = p; p += te;
    f16* kh  = p; p += te;
    f16* vh  = p; p += te;
    f16* Op0 = p; p += te;
    f16* Op1 = p; p += te;
    f16* ch  = p; p += te;
    float* l0 = (float*)p;
    float* l1 = l0 + (size_t)B * NH * T_LEN;

    dim3 blk(256);
    prep_kernel<<<dim3(16, 8, 3 * B + 8), blk, 0, stream>>>(
        x_q, x_k, x_v, Wq, Wk, Wv, Wo, xTq, xTk, xTv, wqh, wkh, wvh, woh, B);
    proj_qkv<<<dim3(B * 8, 8, 3), blk, 0, stream>>>(
        xTq, xTk, xTv, wqh, wkh, wvh, bq, bk, bv, qh, kh, vh);
    attn_mfma<<<dim3(T_LEN / 64, NH, 2 * B), blk, 0, stream>>>(
        qh, kh, vh, erk, erv, Op0, Op1, l0, l1);
    combine_kernel<<<dim3(B * 256), blk, 0, stream>>>(Op0, Op1, l0, l1, ch);
    proj_out<<<dim3(B * 16, 8), blk, 0, stream>>>(ch, woh, bo, (float*)d_out);
}

// Round 6
// 158.435 us; speedup vs baseline: 1.3468x; 1.3468x over previous
//
#include <hip/hip_runtime.h>

#define T_LEN 1024
#define NH 8
#define DH 64
#define CCH 512
#define LOG2E 1.44269504088896340736f

typedef _Float16 f16;
typedef _Float16 f16x8 __attribute__((ext_vector_type(8)));
typedef _Float16 f16x4 __attribute__((ext_vector_type(4)));
typedef float f32x4 __attribute__((ext_vector_type(4)));

// async global->LDS DMA, 16B per lane. LDS dest must equal wave-uniform base + lane*16.
__device__ __forceinline__ void dma16(const void* g, void* l)
{
    __builtin_amdgcn_global_load_lds((const __attribute__((address_space(1))) void*)g,
                                     (__attribute__((address_space(3))) void*)l, 16, 0, 0);
}

// ---------------------------------------------------------------------------
// prep: fused [transpose+cvt x -> xT fp16 [b*t][c]] and [W fp32 -> fp16].
// grid(16, 8, 3B + 8), block 256.
// ---------------------------------------------------------------------------
__global__ __launch_bounds__(256)
void prep_kernel(const float* __restrict__ x0, const float* __restrict__ x1,
                 const float* __restrict__ x2, const float* __restrict__ W0,
                 const float* __restrict__ W1, const float* __restrict__ W2,
                 const float* __restrict__ W3, f16* __restrict__ o0,
                 f16* __restrict__ o1, f16* __restrict__ o2, f16* __restrict__ w0,
                 f16* __restrict__ w1, f16* __restrict__ w2, f16* __restrict__ w3,
                 int B)
{
    const int z = blockIdx.z;
    if (z < 3 * B) {
        const int t0 = blockIdx.x * 64, c0 = blockIdx.y * 64;
        const int which = z / B, b = z % B;
        const float* x = (which == 0) ? x0 : (which == 1) ? x1 : x2;
        f16* o = (which == 0) ? o0 : (which == 1) ? o1 : o2;

        __shared__ float L[64 * 68];
        const int cl = threadIdx.x & 63, g = threadIdx.x >> 6;
        const float* src = x + ((size_t)(b * CCH + c0 + cl)) * T_LEN + t0 + g * 16;
        #pragma unroll
        for (int j = 0; j < 4; ++j)
            *(float4*)&L[cl * 68 + g * 16 + 4 * j] = *(const float4*)&src[4 * j];
        __syncthreads();
        const int tl = threadIdx.x & 63, cg = (threadIdx.x >> 6) * 16;
        f16 h[16];
        #pragma unroll
        for (int j = 0; j < 16; ++j) h[j] = (f16)L[(cg + j) * 68 + tl];
        f16* dst = o + ((size_t)(b * T_LEN + t0 + tl)) * CCH + c0 + cg;
        *(f16x8*)&dst[0] = *(f16x8*)&h[0];
        *(f16x8*)&dst[8] = *(f16x8*)&h[8];
    } else {
        const int slice = z - 3 * B;
        size_t i = ((size_t)(slice * 128 + blockIdx.y * 16 + blockIdx.x) * 256 + threadIdx.x) * 4;
        const int wi = (int)(i >> 18);
        const size_t off = i & 262143;
        const float* src = (wi == 0) ? W0 : (wi == 1) ? W1 : (wi == 2) ? W2 : W3;
        f16* dst = (wi == 0) ? w0 : (wi == 1) ? w1 : (wi == 2) ? w2 : w3;
        float4 v4 = *(const float4*)&src[off];
        f16x4 h = {(f16)v4.x, (f16)v4.y, (f16)v4.z, (f16)v4.w};
        *(f16x4*)&dst[off] = h;
    }
}

// ---------------------------------------------------------------------------
// Fused q/k/v projections (R4 version): 128(t)x64(o) tile, BK=64, dbuf DMA
// staging for both operands, XOR-swizzled LDS. grid(B*8, 8, 3), block 256.
// ---------------------------------------------------------------------------
__global__ __launch_bounds__(256)
void proj_qkv(const f16* __restrict__ xq, const f16* __restrict__ xk,
              const f16* __restrict__ xv, const f16* __restrict__ wq,
              const f16* __restrict__ wk, const f16* __restrict__ wv,
              const float* __restrict__ bq, const float* __restrict__ bk,
              const float* __restrict__ bv, f16* __restrict__ qo,
              f16* __restrict__ ko, f16* __restrict__ vo)
{
    const int which = blockIdx.z;
    const f16* X = (which == 0) ? xq : (which == 1) ? xk : xv;
    const f16* W = (which == 0) ? wq : (which == 1) ? wk : wv;
    const float* bias = (which == 0) ? bq : (which == 1) ? bk : bv;
    const float scale = (which == 0) ? 0.125f * LOG2E : 1.0f;

    const int r0 = blockIdx.x * 128;
    const int o0 = blockIdx.y * 64;
    const int tid = threadIdx.x;
    const int w = tid >> 6, lane = tid & 63;
    const int quad = lane >> 4, l15 = lane & 15;

    __shared__ __align__(16) f16 Xs[2][128 * 64];
    __shared__ __align__(16) f16 Ws[2][64 * 64];

    const int srow = tid >> 3;
    const int scol = ((tid & 7) ^ (srow & 7)) << 3;

    const f16* Xg = X + (size_t)(r0 + srow) * CCH + scol;
    const f16* Wg = W + (size_t)(o0 + srow) * CCH + scol;

    #pragma unroll
    for (int j = 0; j < 4; ++j)
        dma16(Xg + (size_t)(32 * j) * CCH, &Xs[0][(size_t)tid * 8 + j * 2048]);
    #pragma unroll
    for (int j = 0; j < 2; ++j)
        dma16(Wg + (size_t)(32 * j) * CCH, &Ws[0][(size_t)tid * 8 + j * 2048]);

    f32x4 acc[8] = {};

    for (int kc = 0; kc < 8; ++kc) {
        __syncthreads();   // drains DMA for chunk kc
        if (kc < 7) {
            const int bf = (kc + 1) & 1, c1 = (kc + 1) * 64;
            #pragma unroll
            for (int j = 0; j < 4; ++j)
                dma16(Xg + c1 + (size_t)(32 * j) * CCH, &Xs[bf][(size_t)tid * 8 + j * 2048]);
            #pragma unroll
            for (int j = 0; j < 2; ++j)
                dma16(Wg + c1 + (size_t)(32 * j) * CCH, &Ws[bf][(size_t)tid * 8 + j * 2048]);
        }
        const int cb = kc & 1;
        #pragma unroll
        for (int ks = 0; ks < 2; ++ks) {
            const int sl = ((ks * 4 + quad) ^ (l15 & 7)) << 3;
            f16x8 xf[2], wf[4];
            #pragma unroll
            for (int im = 0; im < 2; ++im)
                xf[im] = *(const f16x8*)&Xs[cb][(32 * w + 16 * im + l15) * 64 + sl];
            #pragma unroll
            for (int cm = 0; cm < 4; ++cm)
                wf[cm] = *(const f16x8*)&Ws[cb][(16 * cm + l15) * 64 + sl];
            if (which < 2) {
                #pragma unroll
                for (int im = 0; im < 2; ++im)
                    #pragma unroll
                    for (int cm = 0; cm < 4; ++cm)
                        acc[im * 4 + cm] = __builtin_amdgcn_mfma_f32_16x16x32_f16(
                            xf[im], wf[cm], acc[im * 4 + cm], 0, 0, 0);
            } else {
                #pragma unroll
                for (int cm = 0; cm < 4; ++cm)
                    #pragma unroll
                    for (int in = 0; in < 2; ++in)
                        acc[cm * 2 + in] = __builtin_amdgcn_mfma_f32_16x16x32_f16(
                            wf[cm], xf[in], acc[cm * 2 + in], 0, 0, 0);
            }
        }
    }

    if (which < 2) {
        f16* out = (which == 0) ? qo : ko;
        float bl[4];
        #pragma unroll
        for (int cm = 0; cm < 4; ++cm) bl[cm] = bias[o0 + 16 * cm + l15];
        #pragma unroll
        for (int im = 0; im < 2; ++im)
            #pragma unroll
            for (int r = 0; r < 4; ++r) {
                size_t row = (size_t)(r0 + 32 * w + 16 * im + 4 * quad + r) * CCH;
                #pragma unroll
                for (int cm = 0; cm < 4; ++cm)
                    out[row + o0 + 16 * cm + l15] =
                        (f16)((acc[im * 4 + cm][r] + bl[cm]) * scale);
            }
    } else {
        const int bb = r0 >> 10, tb = r0 & 1023;
        #pragma unroll
        for (int cm = 0; cm < 4; ++cm) {
            float4 bv4 = *(const float4*)&bias[o0 + 16 * cm + 4 * quad];
            float bl[4] = {bv4.x, bv4.y, bv4.z, bv4.w};
            #pragma unroll
            for (int r = 0; r < 4; ++r) {
                size_t row = ((size_t)(bb * CCH + o0 + 16 * cm + 4 * quad + r)) * T_LEN;
                #pragma unroll
                for (int in = 0; in < 2; ++in)
                    vo[row + tb + 32 * w + 16 * in + l15] =
                        (f16)(acc[cm * 2 + in][r] + bl[r]);
            }
        }
    }
}

// ---------------------------------------------------------------------------
// MFMA flash attention v4: double-buffered K/V with CROSS-BARRIER DMA
// prefetch. Per iter: barrier_C (drains tile kb) -> S -> exp -> P-store ->
// barrier_A -> issue DMA kb+1 -> PV -> rel-V. The DMA flies across
// PV+relV+S+softmax with no intervening barrier. grid(16, NH, 2B), block 256.
// ---------------------------------------------------------------------------
__global__ __launch_bounds__(256)
void attn_mfma(const f16* __restrict__ q, const f16* __restrict__ kk,
               const f16* __restrict__ v, const float* __restrict__ ekg,
               const float* __restrict__ evg, f16* __restrict__ Op0,
               f16* __restrict__ Op1, float* __restrict__ l0,
               float* __restrict__ l1)
{
    const int t0 = blockIdx.x * 64, h = blockIdx.y;
    const int b = blockIdx.z >> 1, split = blockIdx.z & 1;
    const int tid = threadIdx.x;
    const int w = tid >> 6, lane = tid & 63;
    const int quad = lane >> 4, l15 = lane & 15;

    f16* Op = split ? Op1 : Op0;
    float* lbuf = split ? l1 : l0;

    __shared__ __align__(16) f16 Qs[4096], Ps[4096];
    __shared__ __align__(16) f16 Ks[2][4096], Vs[2][4096];
    __shared__ float eks[576], evs[576];

    const int srow = tid >> 3;
    const int scol = ((tid & 7) ^ (srow & 7)) << 3;

    for (int i = tid; i < 576; i += 256) {
        eks[i] = ekg[h * 576 + i];
        evs[i] = evg[h * 576 + i];
    }

    const int kb0 = split * 8;
    const f16* gk = kk + ((size_t)(b * T_LEN + kb0 * 64 + srow)) * CCH + h * DH + scol;
    const f16* gv = v + ((size_t)(b * CCH + h * DH + srow)) * T_LEN + kb0 * 64 + scol;

    // prologue: Q + tile 0 into buf 0
    dma16(q + ((size_t)(b * T_LEN + t0 + srow)) * CCH + h * DH + scol, &Qs[(size_t)tid * 8]);
    dma16(q + ((size_t)(b * T_LEN + t0 + srow + 32)) * CCH + h * DH + scol, &Qs[((size_t)tid + 256) * 8]);
    dma16(gk, &Ks[0][(size_t)tid * 8]);
    dma16(gk + (size_t)32 * CCH, &Ks[0][((size_t)tid + 256) * 8]);
    dma16(gv, &Vs[0][(size_t)tid * 8]);
    dma16(gv + (size_t)32 * T_LEN, &Vs[0][((size_t)tid + 256) * 8]);
    __syncthreads();

    f16x8 qf[2];
    #pragma unroll
    for (int ks = 0; ks < 2; ++ks)
        qf[ks] = *(const f16x8*)&Qs[(16 * w + l15) * 64 + (((ks * 4 + quad) ^ (l15 & 7)) << 3)];

    const int myt = 16 * w + l15;
    float Ssum = 0.f;
    f32x4 O[4] = {};

    const bool corner_hi = (blockIdx.x == 0) && (split == 1);
    const bool corner_lo = (blockIdx.x == 15) && (split == 0);

    for (int it = 0; it < 8; ++it) {
        const int kb = kb0 + it, cb = it & 1;
        if (it) __syncthreads();   // barrier_C: drains DMA(tile it); prev Ps reads done

        // ----- S^T = K Q^T -----
        f32x4 S[4] = {};
        #pragma unroll
        for (int ks = 0; ks < 2; ++ks) {
            #pragma unroll
            for (int ct = 0; ct < 4; ++ct) {
                f16x8 a = *(const f16x8*)&Ks[cb][(16 * ct + l15) * 64 + (((ks * 4 + quad) ^ (l15 & 7)) << 3)];
                S[ct] = __builtin_amdgcn_mfma_f32_16x16x32_f16(a, qf[ks], S[ct], 0, 0, 0);
            }
        }

        // ----- corner relative-K bias (rare) -----
        if ((corner_hi && kb == 15) || (corner_lo && kb == 0)) {
            const int s0g = kb * 64;
            #pragma unroll
            for (int ct = 0; ct < 4; ++ct)
                #pragma unroll
                for (int r = 0; r < 4; ++r) {
                    int t_g = t0 + myt;
                    int s_g = s0g + 16 * ct + 4 * quad + r;
                    int df = s_g - t_g;
                    if (df >= 1019 && df <= 1023) {
                        const float* ekp = &eks[(df - 1019) * 64];
                        float sacc = 0.f;
                        for (int d = 0; d < 64; ++d)
                            sacc += (float)Qs[myt * 64 + (((d >> 3) ^ (myt & 7)) << 3) + (d & 7)] * ekp[d];
                        S[ct][r] += sacc;
                    } else if (df >= -1023 && df <= -1021) {
                        const float* ekp = &eks[(1029 + df) * 64];
                        const int t2 = myt - 1;
                        float sacc = 0.f;
                        for (int d = 0; d < 64; ++d)
                            sacc += (float)Qs[t2 * 64 + (((d >> 3) ^ (t2 & 7)) << 3) + (d & 7)] * ekp[d];
                        S[ct][r] += sacc;
                    }
                }
        }

        // ----- no-max softmax: P = exp2(S); store Ps (swizzled) -----
        #pragma unroll
        for (int ct = 0; ct < 4; ++ct) {
            f16x4 pk_;
            #pragma unroll
            for (int r = 0; r < 4; ++r) {
                float p = exp2f(S[ct][r]);
                Ssum += p;
                pk_[r] = (f16)p;
            }
            int colh = (((2 * ct + (quad >> 1)) ^ (myt & 7)) << 3) + (quad & 1) * 4;
            *(f16x4*)&Ps[myt * 64 + colh] = pk_;
        }
        __syncthreads();   // barrier_A: Ps visible (no DMA outstanding here)

        // ----- issue prefetch DMA for tile it+1 (flies until next barrier_C)
        if (it < 7) {
            const int nb = cb ^ 1;
            dma16(gk + (size_t)((it + 1) * 64) * CCH, &Ks[nb][(size_t)tid * 8]);
            dma16(gk + (size_t)((it + 1) * 64 + 32) * CCH, &Ks[nb][((size_t)tid + 256) * 8]);
            dma16(gv + (it + 1) * 64, &Vs[nb][(size_t)tid * 8]);
            dma16(gv + (size_t)32 * T_LEN + (it + 1) * 64, &Vs[nb][((size_t)tid + 256) * 8]);
        }

        // ----- O += P V -----
        #pragma unroll
        for (int ks = 0; ks < 2; ++ks) {
            f16x8 a = *(const f16x8*)&Ps[(16 * w + l15) * 64 + (((ks * 4 + quad) ^ (l15 & 7)) << 3)];
            #pragma unroll
            for (int ct = 0; ct < 4; ++ct) {
                f16x8 bf = *(const f16x8*)&Vs[cb][(16 * ct + l15) * 64 + (((ks * 4 + quad) ^ (l15 & 7)) << 3)];
                O[ct] = __builtin_amdgcn_mfma_f32_16x16x32_f16(a, bf, O[ct], 0, 0, 0);
            }
        }

        // ----- windowed relative-V -----
        const int s0g = kb * 64;
        if (s0g <= t0 + 67 && s0g + 63 >= t0 - 4) {
            #pragma unroll
            for (int r = 0; r < 4; ++r) {
                int t_loc = 16 * w + 4 * quad + r;
                int t_g = t0 + t_loc;
                int slo = max(s0g, t_g - 4), shi = min(s0g + 63, t_g + 4);
                for (int s = slo; s <= shi; ++s) {
                    int sl = s - s0g;
                    float p = (float)Ps[t_loc * 64 + (((sl >> 3) ^ (t_loc & 7)) << 3) + (sl & 7)];
                    const float* evp = &evs[(s - t_g + 4) * 64];
                    #pragma unroll
                    for (int ct = 0; ct < 4; ++ct)
                        O[ct][r] += p * evp[16 * ct + l15];
                }
            }
        }
    }

    Ssum += __shfl_xor(Ssum, 16);
    Ssum += __shfl_xor(Ssum, 32);
    if (quad == 0)
        lbuf[((size_t)b * NH + h) * T_LEN + t0 + myt] = Ssum;

    #pragma unroll
    for (int r = 0; r < 4; ++r) {
        int t_g = t0 + 16 * w + 4 * quad + r;
        size_t rowo = ((size_t)(b * T_LEN + t_g)) * CCH + h * DH;
        #pragma unroll
        for (int ct = 0; ct < 4; ++ct)
            Op[rowo + 16 * ct + l15] = (f16)O[ct][r];
    }
}

// ---------------------------------------------------------------------------
// Output projection with FUSED split-combine: Cs staging computes
// (Op0+Op1)*rl on the fly (rl precomputed per (row,head) into LDS).
// 64(o)x128(t) tile, BK=64, dbuf (Ws via DMA, Cs via VGPR staging).
// grid(B*8, 8), block 256. fp32 out [b][o][t].
// ---------------------------------------------------------------------------
__global__ __launch_bounds__(256)
void proj_out(const f16* __restrict__ Op0, const f16* __restrict__ Op1,
              const float* __restrict__ l0, const float* __restrict__ l1,
              const f16* __restrict__ Wo, const float* __restrict__ bo,
              float* __restrict__ out)
{
    const int r0 = blockIdx.x * 128;   // flat (b,t)
    const int o0 = blockIdx.y * 64;
    const int tid = threadIdx.x;
    const int w = tid >> 6, lane = tid & 63;
    const int quad = lane >> 4, l15 = lane & 15;

    __shared__ __align__(16) f16 Cs[2][128 * 64];
    __shared__ __align__(16) f16 Ws[2][64 * 64];
    __shared__ float rls[128 * 8];     // [row][head]

    const int srow = tid >> 3;         // 0..31
    const int slot = tid & 7;
    const int scol = (slot ^ (srow & 7)) << 3;

    // rl table: 1/(l0+l1) per (tile row, head)
    for (int idx = tid; idx < 1024; idx += 256) {
        int row = idx >> 3, hh = idx & 7;
        size_t gr = r0 + row;
        size_t li = ((gr >> 10) * NH + hh) * T_LEN + (gr & 1023);
        rls[idx] = 1.0f / (l0[li] + l1[li]);
    }
    __syncthreads();

    const f16* Wg = Wo + (size_t)(o0 + srow) * CCH + scol;

    // stage chunk 0: Ws via DMA, Cs via combine
    #pragma unroll
    for (int j = 0; j < 2; ++j)
        dma16(Wg + (size_t)(32 * j) * CCH, &Ws[0][(size_t)tid * 8 + j * 2048]);
    #pragma unroll
    for (int j = 0; j < 4; ++j) {
        int row = srow + 32 * j;
        size_t src = (size_t)(r0 + row) * CCH + scol;   // chunk 0: head 0
        f16x8 a0 = *(const f16x8*)&Op0[src];
        f16x8 a1 = *(const f16x8*)&Op1[src];
        float rl = rls[row * 8];
        f16 hx[8];
        #pragma unroll
        for (int e = 0; e < 8; ++e)
            hx[e] = (f16)(((float)a0[e] + (float)a1[e]) * rl);
        *(f16x8*)&Cs[0][row * 64 + slot * 8] = *(f16x8*)hx;
    }

    f32x4 acc[8] = {};

    for (int kc = 0; kc < 8; ++kc) {
        __syncthreads();   // drains Ws DMA + Cs ds_writes for chunk kc
        if (kc < 7) {
            const int bf = (kc + 1) & 1, c1 = (kc + 1) * 64;
            #pragma unroll
            for (int j = 0; j < 2; ++j)
                dma16(Wg + c1 + (size_t)(32 * j) * CCH, &Ws[bf][(size_t)tid * 8 + j * 2048]);
            #pragma unroll
            for (int j = 0; j < 4; ++j) {
                int row = srow + 32 * j;
                size_t src = (size_t)(r0 + row) * CCH + c1 + scol;
                f16x8 a0 = *(const f16x8*)&Op0[src];
                f16x8 a1 = *(const f16x8*)&Op1[src];
                float rl = rls[row * 8 + kc + 1];
                f16 hx[8];
                #pragma unroll
                for (int e = 0; e < 8; ++e)
                    hx[e] = (f16)(((float)a0[e] + (float)a1[e]) * rl);
                *(f16x8*)&Cs[bf][row * 64 + slot * 8] = *(f16x8*)hx;
            }
        }
        const int cb = kc & 1;
        #pragma unroll
        for (int ks = 0; ks < 2; ++ks) {
            const int sl = ((ks * 4 + quad) ^ (l15 & 7)) << 3;
            f16x8 cf[2], wf[4];
            #pragma unroll
            for (int in = 0; in < 2; ++in)
                cf[in] = *(const f16x8*)&Cs[cb][(32 * w + 16 * in + l15) * 64 + sl];
            #pragma unroll
            for (int cm = 0; cm < 4; ++cm)
                wf[cm] = *(const f16x8*)&Ws[cb][(16 * cm + l15) * 64 + sl];
            #pragma unroll
            for (int cm = 0; cm < 4; ++cm)
                #pragma unroll
                for (int in = 0; in < 2; ++in)
                    acc[cm * 2 + in] = __builtin_amdgcn_mfma_f32_16x16x32_f16(
                        wf[cm], cf[in], acc[cm * 2 + in], 0, 0, 0);
        }
    }

    const int bb = r0 >> 10, tb = r0 & 1023;
    #pragma unroll
    for (int cm = 0; cm < 4; ++cm) {
        float4 bv4 = *(const float4*)&bo[o0 + 16 * cm + 4 * quad];
        float bl[4] = {bv4.x, bv4.y, bv4.z, bv4.w};
        #pragma unroll
        for (int r = 0; r < 4; ++r) {
            size_t row = ((size_t)(bb * CCH + o0 + 16 * cm + 4 * quad + r)) * T_LEN;
            #pragma unroll
            for (int in = 0; in < 2; ++in)
                out[row + tb + 32 * w + 16 * in + l15] = acc[cm * 2 + in][r] + bl[r];
        }
    }
}

// ---------------------------------------------------------------------------
extern "C" void kernel_launch(void* const* d_in, const int* in_sizes, int n_in,
                              void* d_out, int out_size, void* d_ws, size_t ws_size,
                              hipStream_t stream)
{
    const float* x_q = (const float*)d_in[0];
    const float* x_k = (const float*)d_in[1];
    const float* x_v = (const float*)d_in[2];
    const float* Wq  = (const float*)d_in[3];
    const float* bq  = (const float*)d_in[4];
    const float* Wk  = (const float*)d_in[5];
    const float* bk  = (const float*)d_in[6];
    const float* Wv  = (const float*)d_in[7];
    const float* bv  = (const float*)d_in[8];
    const float* Wo  = (const float*)d_in[9];
    const float* bo  = (const float*)d_in[10];
    const float* erk = (const float*)d_in[11];
    const float* erv = (const float*)d_in[12];

    const int B = in_sizes[0] / (CCH * T_LEN);
    const size_t te = (size_t)B * CCH * T_LEN;
    const size_t we = (size_t)CCH * CCH;

    f16* p = (f16*)d_ws;
    f16* xTq = p; p += te;
    f16* xTk = p; p += te;
    f16* xTv = p; p += te;
    f16* wqh = p; p += we;
    f16* wkh = p; p += we;
    f16* wvh = p; p += we;
    f16* woh = p; p += we;
    f16* qh  = p; p += te;
    f16* kh  = p; p += te;
    f16* vh  = p; p += te;
    f16* Op0 = p; p += te;
    f16* Op1 = p; p += te;
    float* l0 = (float*)p;
    float* l1 = l0 + (size_t)B * NH * T_LEN;

    dim3 blk(256);
    prep_kernel<<<dim3(16, 8, 3 * B + 8), blk, 0, stream>>>(
        x_q, x_k, x_v, Wq, Wk, Wv, Wo, xTq, xTk, xTv, wqh, wkh, wvh, woh, B);
    proj_qkv<<<dim3(B * 8, 8, 3), blk, 0, stream>>>(
        xTq, xTk, xTv, wqh, wkh, wvh, bq, bk, bv, qh, kh, vh);
    attn_mfma<<<dim3(T_LEN / 64, NH, 2 * B), blk, 0, stream>>>(
        qh, kh, vh, erk, erv, Op0, Op1, l0, l1);
    proj_out<<<dim3(B * 8, 8), blk, 0, stream>>>(
        Op0, Op1, l0, l1, woh, bo, (float*)d_out);
}

// Round 7
// 152.726 us; speedup vs baseline: 1.3971x; 1.0374x over previous
//
#include <hip/hip_runtime.h>

#define T_LEN 1024
#define NH 8
#define DH 64
#define CCH 512
#define LOG2E 1.44269504088896340736f

typedef _Float16 f16;
typedef _Float16 f16x8 __attribute__((ext_vector_type(8)));
typedef _Float16 f16x4 __attribute__((ext_vector_type(4)));
typedef float f32x4 __attribute__((ext_vector_type(4)));

// async global->LDS DMA, 16B per lane. LDS dest must equal wave-uniform base + lane*16.
__device__ __forceinline__ void dma16(const void* g, void* l)
{
    __builtin_amdgcn_global_load_lds((const __attribute__((address_space(1))) void*)g,
                                     (__attribute__((address_space(3))) void*)l, 16, 0, 0);
}

// ---------------------------------------------------------------------------
// prep: fused [transpose+cvt x -> xT fp16 [b*t][c]] and [W fp32 -> fp16].
// grid(16, 8, 3B + 8), block 256.
// ---------------------------------------------------------------------------
__global__ __launch_bounds__(256)
void prep_kernel(const float* __restrict__ x0, const float* __restrict__ x1,
                 const float* __restrict__ x2, const float* __restrict__ W0,
                 const float* __restrict__ W1, const float* __restrict__ W2,
                 const float* __restrict__ W3, f16* __restrict__ o0,
                 f16* __restrict__ o1, f16* __restrict__ o2, f16* __restrict__ w0,
                 f16* __restrict__ w1, f16* __restrict__ w2, f16* __restrict__ w3,
                 int B)
{
    const int z = blockIdx.z;
    if (z < 3 * B) {
        const int t0 = blockIdx.x * 64, c0 = blockIdx.y * 64;
        const int which = z / B, b = z % B;
        const float* x = (which == 0) ? x0 : (which == 1) ? x1 : x2;
        f16* o = (which == 0) ? o0 : (which == 1) ? o1 : o2;

        __shared__ float L[64 * 68];
        const int cl = threadIdx.x & 63, g = threadIdx.x >> 6;
        const float* src = x + ((size_t)(b * CCH + c0 + cl)) * T_LEN + t0 + g * 16;
        #pragma unroll
        for (int j = 0; j < 4; ++j)
            *(float4*)&L[cl * 68 + g * 16 + 4 * j] = *(const float4*)&src[4 * j];
        __syncthreads();
        const int tl = threadIdx.x & 63, cg = (threadIdx.x >> 6) * 16;
        f16 h[16];
        #pragma unroll
        for (int j = 0; j < 16; ++j) h[j] = (f16)L[(cg + j) * 68 + tl];
        f16* dst = o + ((size_t)(b * T_LEN + t0 + tl)) * CCH + c0 + cg;
        *(f16x8*)&dst[0] = *(f16x8*)&h[0];
        *(f16x8*)&dst[8] = *(f16x8*)&h[8];
    } else {
        const int slice = z - 3 * B;
        size_t i = ((size_t)(slice * 128 + blockIdx.y * 16 + blockIdx.x) * 256 + threadIdx.x) * 4;
        const int wi = (int)(i >> 18);
        const size_t off = i & 262143;
        const float* src = (wi == 0) ? W0 : (wi == 1) ? W1 : (wi == 2) ? W2 : W3;
        f16* dst = (wi == 0) ? w0 : (wi == 1) ? w1 : (wi == 2) ? w2 : w3;
        float4 v4 = *(const float4*)&src[off];
        f16x4 h = {(f16)v4.x, (f16)v4.y, (f16)v4.z, (f16)v4.w};
        *(f16x4*)&dst[off] = h;
    }
}

// ---------------------------------------------------------------------------
// Fused q/k/v projections: 128(t)x64(o) tile, BK=64, dbuf DMA staging,
// XOR-swizzled LDS. grid(B*8, 8, 3), block 256. (unchanged from R6)
// ---------------------------------------------------------------------------
__global__ __launch_bounds__(256)
void proj_qkv(const f16* __restrict__ xq, const f16* __restrict__ xk,
              const f16* __restrict__ xv, const f16* __restrict__ wq,
              const f16* __restrict__ wk, const f16* __restrict__ wv,
              const float* __restrict__ bq, const float* __restrict__ bk,
              const float* __restrict__ bv, f16* __restrict__ qo,
              f16* __restrict__ ko, f16* __restrict__ vo)
{
    const int which = blockIdx.z;
    const f16* X = (which == 0) ? xq : (which == 1) ? xk : xv;
    const f16* W = (which == 0) ? wq : (which == 1) ? wk : wv;
    const float* bias = (which == 0) ? bq : (which == 1) ? bk : bv;
    const float scale = (which == 0) ? 0.125f * LOG2E : 1.0f;

    const int r0 = blockIdx.x * 128;
    const int o0 = blockIdx.y * 64;
    const int tid = threadIdx.x;
    const int w = tid >> 6, lane = tid & 63;
    const int quad = lane >> 4, l15 = lane & 15;

    __shared__ __align__(16) f16 Xs[2][128 * 64];
    __shared__ __align__(16) f16 Ws[2][64 * 64];

    const int srow = tid >> 3;
    const int scol = ((tid & 7) ^ (srow & 7)) << 3;

    const f16* Xg = X + (size_t)(r0 + srow) * CCH + scol;
    const f16* Wg = W + (size_t)(o0 + srow) * CCH + scol;

    #pragma unroll
    for (int j = 0; j < 4; ++j)
        dma16(Xg + (size_t)(32 * j) * CCH, &Xs[0][(size_t)tid * 8 + j * 2048]);
    #pragma unroll
    for (int j = 0; j < 2; ++j)
        dma16(Wg + (size_t)(32 * j) * CCH, &Ws[0][(size_t)tid * 8 + j * 2048]);

    f32x4 acc[8] = {};

    for (int kc = 0; kc < 8; ++kc) {
        __syncthreads();
        if (kc < 7) {
            const int bf = (kc + 1) & 1, c1 = (kc + 1) * 64;
            #pragma unroll
            for (int j = 0; j < 4; ++j)
                dma16(Xg + c1 + (size_t)(32 * j) * CCH, &Xs[bf][(size_t)tid * 8 + j * 2048]);
            #pragma unroll
            for (int j = 0; j < 2; ++j)
                dma16(Wg + c1 + (size_t)(32 * j) * CCH, &Ws[bf][(size_t)tid * 8 + j * 2048]);
        }
        const int cb = kc & 1;
        #pragma unroll
        for (int ks = 0; ks < 2; ++ks) {
            const int sl = ((ks * 4 + quad) ^ (l15 & 7)) << 3;
            f16x8 xf[2], wf[4];
            #pragma unroll
            for (int im = 0; im < 2; ++im)
                xf[im] = *(const f16x8*)&Xs[cb][(32 * w + 16 * im + l15) * 64 + sl];
            #pragma unroll
            for (int cm = 0; cm < 4; ++cm)
                wf[cm] = *(const f16x8*)&Ws[cb][(16 * cm + l15) * 64 + sl];
            if (which < 2) {
                #pragma unroll
                for (int im = 0; im < 2; ++im)
                    #pragma unroll
                    for (int cm = 0; cm < 4; ++cm)
                        acc[im * 4 + cm] = __builtin_amdgcn_mfma_f32_16x16x32_f16(
                            xf[im], wf[cm], acc[im * 4 + cm], 0, 0, 0);
            } else {
                #pragma unroll
                for (int cm = 0; cm < 4; ++cm)
                    #pragma unroll
                    for (int in = 0; in < 2; ++in)
                        acc[cm * 2 + in] = __builtin_amdgcn_mfma_f32_16x16x32_f16(
                            wf[cm], xf[in], acc[cm * 2 + in], 0, 0, 0);
            }
        }
    }

    if (which < 2) {
        f16* out = (which == 0) ? qo : ko;
        float bl[4];
        #pragma unroll
        for (int cm = 0; cm < 4; ++cm) bl[cm] = bias[o0 + 16 * cm + l15];
        #pragma unroll
        for (int im = 0; im < 2; ++im)
            #pragma unroll
            for (int r = 0; r < 4; ++r) {
                size_t row = (size_t)(r0 + 32 * w + 16 * im + 4 * quad + r) * CCH;
                #pragma unroll
                for (int cm = 0; cm < 4; ++cm)
                    out[row + o0 + 16 * cm + l15] =
                        (f16)((acc[im * 4 + cm][r] + bl[cm]) * scale);
            }
    } else {
        const int bb = r0 >> 10, tb = r0 & 1023;
        #pragma unroll
        for (int cm = 0; cm < 4; ++cm) {
            float4 bv4 = *(const float4*)&bias[o0 + 16 * cm + 4 * quad];
            float bl[4] = {bv4.x, bv4.y, bv4.z, bv4.w};
            #pragma unroll
            for (int r = 0; r < 4; ++r) {
                size_t row = ((size_t)(bb * CCH + o0 + 16 * cm + 4 * quad + r)) * T_LEN;
                #pragma unroll
                for (int in = 0; in < 2; ++in)
                    vo[row + tb + 32 * w + 16 * in + l15] =
                        (f16)(acc[cm * 2 + in][r] + bl[r]);
            }
        }
    }
}

// ---------------------------------------------------------------------------
// MFMA flash attention v5: NO split-K — one block per (b,h,64-row Q tile),
// 512 blocks all co-resident (3 blocks/CU LDS limit). 16 K-iters with
// double-buffered cross-barrier DMA prefetch. Normalizes in-kernel and
// writes final ctx f16 [b*t][c] (no partials, no combine pass).
// grid(16, NH, B), block 256.
// ---------------------------------------------------------------------------
__global__ __launch_bounds__(256)
void attn_mfma(const f16* __restrict__ q, const f16* __restrict__ kk,
               const f16* __restrict__ v, const float* __restrict__ ekg,
               const float* __restrict__ evg, f16* __restrict__ ctx)
{
    const int t0 = blockIdx.x * 64, h = blockIdx.y, b = blockIdx.z;
    const int tid = threadIdx.x;
    const int w = tid >> 6, lane = tid & 63;
    const int quad = lane >> 4, l15 = lane & 15;

    __shared__ __align__(16) f16 Qs[4096], Ps[4096];
    __shared__ __align__(16) f16 Ks[2][4096], Vs[2][4096];
    __shared__ float eks[576], evs[576];
    __shared__ float ls[64];

    const int srow = tid >> 3;
    const int scol = ((tid & 7) ^ (srow & 7)) << 3;

    for (int i = tid; i < 576; i += 256) {
        eks[i] = ekg[h * 576 + i];
        evs[i] = evg[h * 576 + i];
    }

    const f16* gk = kk + ((size_t)(b * T_LEN + srow)) * CCH + h * DH + scol;
    const f16* gv = v + ((size_t)(b * CCH + h * DH + srow)) * T_LEN + scol;

    // prologue: Q + tile 0 into buf 0
    dma16(q + ((size_t)(b * T_LEN + t0 + srow)) * CCH + h * DH + scol, &Qs[(size_t)tid * 8]);
    dma16(q + ((size_t)(b * T_LEN + t0 + srow + 32)) * CCH + h * DH + scol, &Qs[((size_t)tid + 256) * 8]);
    dma16(gk, &Ks[0][(size_t)tid * 8]);
    dma16(gk + (size_t)32 * CCH, &Ks[0][((size_t)tid + 256) * 8]);
    dma16(gv, &Vs[0][(size_t)tid * 8]);
    dma16(gv + (size_t)32 * T_LEN, &Vs[0][((size_t)tid + 256) * 8]);
    __syncthreads();

    f16x8 qf[2];
    #pragma unroll
    for (int ks = 0; ks < 2; ++ks)
        qf[ks] = *(const f16x8*)&Qs[(16 * w + l15) * 64 + (((ks * 4 + quad) ^ (l15 & 7)) << 3)];

    const int myt = 16 * w + l15;
    float Ssum = 0.f;
    f32x4 O[4] = {};

    const bool corner_hi = (blockIdx.x == 0);
    const bool corner_lo = (blockIdx.x == 15);

    for (int it = 0; it < 16; ++it) {
        const int kb = it, cb = it & 1;
        if (it) __syncthreads();   // barrier_C: drains DMA(tile it); prev Ps reads done

        // ----- S^T = K Q^T -----
        f32x4 S[4] = {};
        #pragma unroll
        for (int ks = 0; ks < 2; ++ks) {
            #pragma unroll
            for (int ct = 0; ct < 4; ++ct) {
                f16x8 a = *(const f16x8*)&Ks[cb][(16 * ct + l15) * 64 + (((ks * 4 + quad) ^ (l15 & 7)) << 3)];
                S[ct] = __builtin_amdgcn_mfma_f32_16x16x32_f16(a, qf[ks], S[ct], 0, 0, 0);
            }
        }

        // ----- corner relative-K bias (rare) -----
        if ((corner_hi && kb == 15) || (corner_lo && kb == 0)) {
            const int s0g = kb * 64;
            #pragma unroll
            for (int ct = 0; ct < 4; ++ct)
                #pragma unroll
                for (int r = 0; r < 4; ++r) {
                    int t_g = t0 + myt;
                    int s_g = s0g + 16 * ct + 4 * quad + r;
                    int df = s_g - t_g;
                    if (df >= 1019 && df <= 1023) {
                        const float* ekp = &eks[(df - 1019) * 64];
                        float sacc = 0.f;
                        for (int d = 0; d < 64; ++d)
                            sacc += (float)Qs[myt * 64 + (((d >> 3) ^ (myt & 7)) << 3) + (d & 7)] * ekp[d];
                        S[ct][r] += sacc;
                    } else if (df >= -1023 && df <= -1021) {
                        const float* ekp = &eks[(1029 + df) * 64];
                        const int t2 = myt - 1;
                        float sacc = 0.f;
                        for (int d = 0; d < 64; ++d)
                            sacc += (float)Qs[t2 * 64 + (((d >> 3) ^ (t2 & 7)) << 3) + (d & 7)] * ekp[d];
                        S[ct][r] += sacc;
                    }
                }
        }

        // ----- no-max softmax: P = exp2(S); store Ps (swizzled) -----
        #pragma unroll
        for (int ct = 0; ct < 4; ++ct) {
            f16x4 pk_;
            #pragma unroll
            for (int r = 0; r < 4; ++r) {
                float p = exp2f(S[ct][r]);
                Ssum += p;
                pk_[r] = (f16)p;
            }
            int colh = (((2 * ct + (quad >> 1)) ^ (myt & 7)) << 3) + (quad & 1) * 4;
            *(f16x4*)&Ps[myt * 64 + colh] = pk_;
        }
        __syncthreads();   // barrier_A: Ps visible (no DMA outstanding here)

        // ----- issue prefetch DMA for tile it+1 (flies until next barrier_C)
        if (it < 15) {
            const int nb = cb ^ 1;
            dma16(gk + (size_t)((it + 1) * 64) * CCH, &Ks[nb][(size_t)tid * 8]);
            dma16(gk + (size_t)((it + 1) * 64 + 32) * CCH, &Ks[nb][((size_t)tid + 256) * 8]);
            dma16(gv + (it + 1) * 64, &Vs[nb][(size_t)tid * 8]);
            dma16(gv + (size_t)32 * T_LEN + (it + 1) * 64, &Vs[nb][((size_t)tid + 256) * 8]);
        }

        // ----- O += P V -----
        #pragma unroll
        for (int ks = 0; ks < 2; ++ks) {
            f16x8 a = *(const f16x8*)&Ps[(16 * w + l15) * 64 + (((ks * 4 + quad) ^ (l15 & 7)) << 3)];
            #pragma unroll
            for (int ct = 0; ct < 4; ++ct) {
                f16x8 bf = *(const f16x8*)&Vs[cb][(16 * ct + l15) * 64 + (((ks * 4 + quad) ^ (l15 & 7)) << 3)];
                O[ct] = __builtin_amdgcn_mfma_f32_16x16x32_f16(a, bf, O[ct], 0, 0, 0);
            }
        }

        // ----- windowed relative-V -----
        const int s0g = kb * 64;
        if (s0g <= t0 + 67 && s0g + 63 >= t0 - 4) {
            #pragma unroll
            for (int r = 0; r < 4; ++r) {
                int t_loc = 16 * w + 4 * quad + r;
                int t_g = t0 + t_loc;
                int slo = max(s0g, t_g - 4), shi = min(s0g + 63, t_g + 4);
                for (int s = slo; s <= shi; ++s) {
                    int sl = s - s0g;
                    float p = (float)Ps[t_loc * 64 + (((sl >> 3) ^ (t_loc & 7)) << 3) + (sl & 7)];
                    const float* evp = &evs[(s - t_g + 4) * 64];
                    #pragma unroll
                    for (int ct = 0; ct < 4; ++ct)
                        O[ct][r] += p * evp[16 * ct + l15];
                }
            }
        }
    }

    // full row-sum (all 16 tiles seen) -> normalize in-kernel.
    Ssum += __shfl_xor(Ssum, 16);
    Ssum += __shfl_xor(Ssum, 32);
    if (quad == 0) ls[myt] = 1.0f / Ssum;   // ls indexed by local t
    __syncthreads();

    #pragma unroll
    for (int r = 0; r < 4; ++r) {
        const int t_loc = 16 * w + 4 * quad + r;
        const float rl = ls[t_loc];
        size_t rowo = ((size_t)(b * T_LEN + t0 + t_loc)) * CCH + h * DH;
        #pragma unroll
        for (int ct = 0; ct < 4; ++ct)
            ctx[rowo + 16 * ct + l15] = (f16)(O[ct][r] * rl);
    }
}

// ---------------------------------------------------------------------------
// Output projection (lean pure GEMM): D[m=o][n=t], A=Wo[o][c], B=ctx[t][c].
// 64x64 tile, BK=64, dbuf DMA both operands. grid(B*16, 8) = 512 blocks.
// fp32 out [b][o][t].
// ---------------------------------------------------------------------------
__global__ __launch_bounds__(256)
void proj_out(const f16* __restrict__ ctx, const f16* __restrict__ Wo,
              const float* __restrict__ bo, float* __restrict__ out)
{
    const int r0 = blockIdx.x * 64;    // flat (b,t)
    const int o0 = blockIdx.y * 64;
    const int tid = threadIdx.x;
    const int w = tid >> 6, lane = tid & 63;
    const int quad = lane >> 4, l15 = lane & 15;

    __shared__ __align__(16) f16 Cs[2][4096];
    __shared__ __align__(16) f16 Ws[2][4096];

    const int srow = tid >> 3;
    const int scol = ((tid & 7) ^ (srow & 7)) << 3;

    const f16* Cg = ctx + (size_t)(r0 + srow) * CCH + scol;
    const f16* Wg = Wo + (size_t)(o0 + srow) * CCH + scol;

    dma16(Cg, &Cs[0][(size_t)tid * 8]);
    dma16(Cg + (size_t)32 * CCH, &Cs[0][((size_t)tid + 256) * 8]);
    dma16(Wg, &Ws[0][(size_t)tid * 8]);
    dma16(Wg + (size_t)32 * CCH, &Ws[0][((size_t)tid + 256) * 8]);

    f32x4 acc[4] = {};

    for (int kc = 0; kc < 8; ++kc) {
        __syncthreads();
        if (kc < 7) {
            const int bf = (kc + 1) & 1, c1 = (kc + 1) * 64;
            dma16(Cg + c1, &Cs[bf][(size_t)tid * 8]);
            dma16(Cg + c1 + (size_t)32 * CCH, &Cs[bf][((size_t)tid + 256) * 8]);
            dma16(Wg + c1, &Ws[bf][(size_t)tid * 8]);
            dma16(Wg + c1 + (size_t)32 * CCH, &Ws[bf][((size_t)tid + 256) * 8]);
        }
        const int cb = kc & 1;
        #pragma unroll
        for (int ks = 0; ks < 2; ++ks) {
            const int sl = ((ks * 4 + quad) ^ (l15 & 7)) << 3;
            f16x8 cf = *(const f16x8*)&Cs[cb][(16 * w + l15) * 64 + sl];
            #pragma unroll
            for (int cm = 0; cm < 4; ++cm) {
                f16x8 wf = *(const f16x8*)&Ws[cb][(16 * cm + l15) * 64 + sl];
                acc[cm] = __builtin_amdgcn_mfma_f32_16x16x32_f16(wf, cf, acc[cm], 0, 0, 0);
            }
        }
    }

    const int bb = r0 >> 10, tb = r0 & 1023;
    #pragma unroll
    for (int cm = 0; cm < 4; ++cm) {
        float4 bv4 = *(const float4*)&bo[o0 + 16 * cm + 4 * quad];
        float bl[4] = {bv4.x, bv4.y, bv4.z, bv4.w};
        #pragma unroll
        for (int r = 0; r < 4; ++r) {
            size_t row = ((size_t)(bb * CCH + o0 + 16 * cm + 4 * quad + r)) * T_LEN;
            out[row + tb + 16 * w + l15] = acc[cm][r] + bl[r];
        }
    }
}

// ---------------------------------------------------------------------------
extern "C" void kernel_launch(void* const* d_in, const int* in_sizes, int n_in,
                              void* d_out, int out_size, void* d_ws, size_t ws_size,
                              hipStream_t stream)
{
    const float* x_q = (const float*)d_in[0];
    const float* x_k = (const float*)d_in[1];
    const float* x_v = (const float*)d_in[2];
    const float* Wq  = (const float*)d_in[3];
    const float* bq  = (const float*)d_in[4];
    const float* Wk  = (const float*)d_in[5];
    const float* bk  = (const float*)d_in[6];
    const float* Wv  = (const float*)d_in[7];
    const float* bv  = (const float*)d_in[8];
    const float* Wo  = (const float*)d_in[9];
    const float* bo  = (const float*)d_in[10];
    const float* erk = (const float*)d_in[11];
    const float* erv = (const float*)d_in[12];

    const int B = in_sizes[0] / (CCH * T_LEN);
    const size_t te = (size_t)B * CCH * T_LEN;
    const size_t we = (size_t)CCH * CCH;

    f16* p = (f16*)d_ws;
    f16* xTq = p; p += te;
    f16* xTk = p; p += te;
    f16* xTv = p; p += te;
    f16* wqh = p; p += we;
    f16* wkh = p; p += we;
    f16* wvh = p; p += we;
    f16* woh = p; p += we;
    f16* qh  = p; p += te;
    f16* kh  = p; p += te;
    f16* vh  = p; p += te;
    f16* ch  = p; p += te;

    dim3 blk(256);
    prep_kernel<<<dim3(16, 8, 3 * B + 8), blk, 0, stream>>>(
        x_q, x_k, x_v, Wq, Wk, Wv, Wo, xTq, xTk, xTv, wqh, wkh, wvh, woh, B);
    proj_qkv<<<dim3(B * 8, 8, 3), blk, 0, stream>>>(
        xTq, xTk, xTv, wqh, wkh, wvh, bq, bk, bv, qh, kh, vh);
    attn_mfma<<<dim3(T_LEN / 64, NH, B), blk, 0, stream>>>(
        qh, kh, vh, erk, erv, ch);
    proj_out<<<dim3(B * 16, 8), blk, 0, stream>>>(
        ch, woh, bo, (float*)d_out);
}

// Round 8
// 152.663 us; speedup vs baseline: 1.3977x; 1.0004x over previous
//
#include <hip/hip_runtime.h>

#define T_LEN 1024
#define NH 8
#define DH 64
#define CCH 512
#define LOG2E 1.44269504088896340736f

typedef _Float16 f16;
typedef _Float16 f16x8 __attribute__((ext_vector_type(8)));
typedef _Float16 f16x4 __attribute__((ext_vector_type(4)));
typedef float f32x4 __attribute__((ext_vector_type(4)));

// async global->LDS DMA, 16B per lane. LDS dest must equal wave-uniform base + lane*16.
__device__ __forceinline__ void dma16(const void* g, void* l)
{
    __builtin_amdgcn_global_load_lds((const __attribute__((address_space(1))) void*)g,
                                     (__attribute__((address_space(3))) void*)l, 16, 0, 0);
}

// ---------------------------------------------------------------------------
// prep: fused [transpose+cvt x -> xT fp16 [b*t][c]] and [W fp32 -> fp16].
// grid(16, 8, 3B + 8), block 256. (unchanged)
// ---------------------------------------------------------------------------
__global__ __launch_bounds__(256)
void prep_kernel(const float* __restrict__ x0, const float* __restrict__ x1,
                 const float* __restrict__ x2, const float* __restrict__ W0,
                 const float* __restrict__ W1, const float* __restrict__ W2,
                 const float* __restrict__ W3, f16* __restrict__ o0,
                 f16* __restrict__ o1, f16* __restrict__ o2, f16* __restrict__ w0,
                 f16* __restrict__ w1, f16* __restrict__ w2, f16* __restrict__ w3,
                 int B)
{
    const int z = blockIdx.z;
    if (z < 3 * B) {
        const int t0 = blockIdx.x * 64, c0 = blockIdx.y * 64;
        const int which = z / B, b = z % B;
        const float* x = (which == 0) ? x0 : (which == 1) ? x1 : x2;
        f16* o = (which == 0) ? o0 : (which == 1) ? o1 : o2;

        __shared__ float L[64 * 68];
        const int cl = threadIdx.x & 63, g = threadIdx.x >> 6;
        const float* src = x + ((size_t)(b * CCH + c0 + cl)) * T_LEN + t0 + g * 16;
        #pragma unroll
        for (int j = 0; j < 4; ++j)
            *(float4*)&L[cl * 68 + g * 16 + 4 * j] = *(const float4*)&src[4 * j];
        __syncthreads();
        const int tl = threadIdx.x & 63, cg = (threadIdx.x >> 6) * 16;
        f16 h[16];
        #pragma unroll
        for (int j = 0; j < 16; ++j) h[j] = (f16)L[(cg + j) * 68 + tl];
        f16* dst = o + ((size_t)(b * T_LEN + t0 + tl)) * CCH + c0 + cg;
        *(f16x8*)&dst[0] = *(f16x8*)&h[0];
        *(f16x8*)&dst[8] = *(f16x8*)&h[8];
    } else {
        const int slice = z - 3 * B;
        size_t i = ((size_t)(slice * 128 + blockIdx.y * 16 + blockIdx.x) * 256 + threadIdx.x) * 4;
        const int wi = (int)(i >> 18);
        const size_t off = i & 262143;
        const float* src = (wi == 0) ? W0 : (wi == 1) ? W1 : (wi == 2) ? W2 : W3;
        f16* dst = (wi == 0) ? w0 : (wi == 1) ? w1 : (wi == 2) ? w2 : w3;
        float4 v4 = *(const float4*)&src[off];
        f16x4 h = {(f16)v4.x, (f16)v4.y, (f16)v4.z, (f16)v4.w};
        *(f16x4*)&dst[off] = h;
    }
}

// ---------------------------------------------------------------------------
// Fused q/k/v projections v2: X A-frags via REGISTER double-buffer (direct
// coalesced global loads, prefetched one chunk ahead — wave-private rows);
// W via DMA-staged dbuf LDS (cross-wave shared). 128(t)x64(o), BK=64.
// grid(B*8, 8, 3), block 256.
// ---------------------------------------------------------------------------
__global__ __launch_bounds__(256)
void proj_qkv(const f16* __restrict__ xq, const f16* __restrict__ xk,
              const f16* __restrict__ xv, const f16* __restrict__ wq,
              const f16* __restrict__ wk, const f16* __restrict__ wv,
              const float* __restrict__ bq, const float* __restrict__ bk,
              const float* __restrict__ bv, f16* __restrict__ qo,
              f16* __restrict__ ko, f16* __restrict__ vo)
{
    const int which = blockIdx.z;
    const f16* X = (which == 0) ? xq : (which == 1) ? xk : xv;
    const f16* W = (which == 0) ? wq : (which == 1) ? wk : wv;
    const float* bias = (which == 0) ? bq : (which == 1) ? bk : bv;
    const float scale = (which == 0) ? 0.125f * LOG2E : 1.0f;

    const int r0 = blockIdx.x * 128;
    const int o0 = blockIdx.y * 64;
    const int tid = threadIdx.x;
    const int w = tid >> 6, lane = tid & 63;
    const int quad = lane >> 4, l15 = lane & 15;

    __shared__ __align__(16) f16 Ws[2][4096];

    const int srow = tid >> 3;
    const int scol = ((tid & 7) ^ (srow & 7)) << 3;
    const f16* Wg = W + (size_t)(o0 + srow) * CCH + scol;

    dma16(Wg, &Ws[0][(size_t)tid * 8]);
    dma16(Wg + (size_t)32 * CCH, &Ws[0][((size_t)tid + 256) * 8]);

    // X fragment base: row r0+32w+16im+l15, k = kc*64 + ks*32 + quad*8
    const f16* xp = X + (size_t)(r0 + 32 * w + l15) * CCH + quad * 8;
    f16x8 xf[2][2];   // [ks][im]
    #pragma unroll
    for (int ks = 0; ks < 2; ++ks)
        #pragma unroll
        for (int im = 0; im < 2; ++im)
            xf[ks][im] = *(const f16x8*)&xp[(size_t)(16 * im) * CCH + ks * 32];

    f32x4 acc[8] = {};

    for (int kc = 0; kc < 8; ++kc) {
        __syncthreads();   // drains W DMA (chunk kc) + X prefetch loads
        if (kc < 7) {
            const int bf = (kc + 1) & 1, c1 = (kc + 1) * 64;
            dma16(Wg + c1, &Ws[bf][(size_t)tid * 8]);
            dma16(Wg + c1 + (size_t)32 * CCH, &Ws[bf][((size_t)tid + 256) * 8]);
        }
        const int nk = ((kc + 1) & 7) * 64;   // kc==7 wraps (loaded, unused)
        f16x8 xn[2][2];
        #pragma unroll
        for (int ks = 0; ks < 2; ++ks)
            #pragma unroll
            for (int im = 0; im < 2; ++im)
                xn[ks][im] = *(const f16x8*)&xp[(size_t)(16 * im) * CCH + nk + ks * 32];

        const int cb = kc & 1;
        #pragma unroll
        for (int ks = 0; ks < 2; ++ks) {
            const int sl = ((ks * 4 + quad) ^ (l15 & 7)) << 3;
            f16x8 wf[4];
            #pragma unroll
            for (int cm = 0; cm < 4; ++cm)
                wf[cm] = *(const f16x8*)&Ws[cb][(16 * cm + l15) * 64 + sl];
            if (which < 2) {
                #pragma unroll
                for (int im = 0; im < 2; ++im)
                    #pragma unroll
                    for (int cm = 0; cm < 4; ++cm)
                        acc[im * 4 + cm] = __builtin_amdgcn_mfma_f32_16x16x32_f16(
                            xf[ks][im], wf[cm], acc[im * 4 + cm], 0, 0, 0);
            } else {
                #pragma unroll
                for (int cm = 0; cm < 4; ++cm)
                    #pragma unroll
                    for (int in = 0; in < 2; ++in)
                        acc[cm * 2 + in] = __builtin_amdgcn_mfma_f32_16x16x32_f16(
                            wf[cm], xf[ks][in], acc[cm * 2 + in], 0, 0, 0);
            }
        }
        #pragma unroll
        for (int ks = 0; ks < 2; ++ks)
            #pragma unroll
            for (int im = 0; im < 2; ++im)
                xf[ks][im] = xn[ks][im];
    }

    if (which < 2) {
        f16* out = (which == 0) ? qo : ko;
        float bl[4];
        #pragma unroll
        for (int cm = 0; cm < 4; ++cm) bl[cm] = bias[o0 + 16 * cm + l15];
        #pragma unroll
        for (int im = 0; im < 2; ++im)
            #pragma unroll
            for (int r = 0; r < 4; ++r) {
                size_t row = (size_t)(r0 + 32 * w + 16 * im + 4 * quad + r) * CCH;
                #pragma unroll
                for (int cm = 0; cm < 4; ++cm)
                    out[row + o0 + 16 * cm + l15] =
                        (f16)((acc[im * 4 + cm][r] + bl[cm]) * scale);
            }
    } else {
        const int bb = r0 >> 10, tb = r0 & 1023;
        #pragma unroll
        for (int cm = 0; cm < 4; ++cm) {
            float4 bv4 = *(const float4*)&bias[o0 + 16 * cm + 4 * quad];
            float bl[4] = {bv4.x, bv4.y, bv4.z, bv4.w};
            #pragma unroll
            for (int r = 0; r < 4; ++r) {
                size_t row = ((size_t)(bb * CCH + o0 + 16 * cm + 4 * quad + r)) * T_LEN;
                #pragma unroll
                for (int in = 0; in < 2; ++in)
                    vo[row + tb + 32 * w + 16 * in + l15] =
                        (f16)(acc[cm * 2 + in][r] + bl[r]);
            }
        }
    }
}

// ---------------------------------------------------------------------------
// MFMA flash attention v6: ONE barrier per K-iter. Ps is wave-private
// (each wave writes/reads only its own 16 rows) -> no barrier between
// P-store and PV/rel-V; in-wave lgkmcnt ordering suffices. K/V prefetch DMA
// issued at iteration TOP -> full-iteration completion window.
// grid(16, NH, B), block 256. Writes final normalized ctx f16 [b*t][c].
// ---------------------------------------------------------------------------
__global__ __launch_bounds__(256)
void attn_mfma(const f16* __restrict__ q, const f16* __restrict__ kk,
               const f16* __restrict__ v, const float* __restrict__ ekg,
               const float* __restrict__ evg, f16* __restrict__ ctx)
{
    const int t0 = blockIdx.x * 64, h = blockIdx.y, b = blockIdx.z;
    const int tid = threadIdx.x;
    const int w = tid >> 6, lane = tid & 63;
    const int quad = lane >> 4, l15 = lane & 15;

    __shared__ __align__(16) f16 Qs[4096], Ps[4096];
    __shared__ __align__(16) f16 Ks[2][4096], Vs[2][4096];
    __shared__ float eks[576], evs[576];
    __shared__ float ls[64];

    const int srow = tid >> 3;
    const int scol = ((tid & 7) ^ (srow & 7)) << 3;

    for (int i = tid; i < 576; i += 256) {
        eks[i] = ekg[h * 576 + i];
        evs[i] = evg[h * 576 + i];
    }

    const f16* gk = kk + ((size_t)(b * T_LEN + srow)) * CCH + h * DH + scol;
    const f16* gv = v + ((size_t)(b * CCH + h * DH + srow)) * T_LEN + scol;

    // prologue: Q + tile 0 into buf 0
    dma16(q + ((size_t)(b * T_LEN + t0 + srow)) * CCH + h * DH + scol, &Qs[(size_t)tid * 8]);
    dma16(q + ((size_t)(b * T_LEN + t0 + srow + 32)) * CCH + h * DH + scol, &Qs[((size_t)tid + 256) * 8]);
    dma16(gk, &Ks[0][(size_t)tid * 8]);
    dma16(gk + (size_t)32 * CCH, &Ks[0][((size_t)tid + 256) * 8]);
    dma16(gv, &Vs[0][(size_t)tid * 8]);
    dma16(gv + (size_t)32 * T_LEN, &Vs[0][((size_t)tid + 256) * 8]);
    __syncthreads();

    f16x8 qf[2];
    #pragma unroll
    for (int ks = 0; ks < 2; ++ks)
        qf[ks] = *(const f16x8*)&Qs[(16 * w + l15) * 64 + (((ks * 4 + quad) ^ (l15 & 7)) << 3)];

    const int myt = 16 * w + l15;
    float Ssum = 0.f;
    f32x4 O[4] = {};

    const bool corner_hi = (blockIdx.x == 0);
    const bool corner_lo = (blockIdx.x == 15);

    for (int it = 0; it < 16; ++it) {
        const int kb = it, cb = it & 1;
        if (it) __syncthreads();   // single barrier: drains DMA(tile it), swaps buffers

        // ----- prefetch DMA for tile it+1 (into other buffer; flies all iter)
        if (it < 15) {
            const int nb = cb ^ 1;
            dma16(gk + (size_t)((it + 1) * 64) * CCH, &Ks[nb][(size_t)tid * 8]);
            dma16(gk + (size_t)((it + 1) * 64 + 32) * CCH, &Ks[nb][((size_t)tid + 256) * 8]);
            dma16(gv + (it + 1) * 64, &Vs[nb][(size_t)tid * 8]);
            dma16(gv + (size_t)32 * T_LEN + (it + 1) * 64, &Vs[nb][((size_t)tid + 256) * 8]);
        }

        // ----- S^T = K Q^T -----
        f32x4 S[4] = {};
        #pragma unroll
        for (int ks = 0; ks < 2; ++ks) {
            #pragma unroll
            for (int ct = 0; ct < 4; ++ct) {
                f16x8 a = *(const f16x8*)&Ks[cb][(16 * ct + l15) * 64 + (((ks * 4 + quad) ^ (l15 & 7)) << 3)];
                S[ct] = __builtin_amdgcn_mfma_f32_16x16x32_f16(a, qf[ks], S[ct], 0, 0, 0);
            }
        }

        // ----- corner relative-K bias (rare) -----
        if ((corner_hi && kb == 15) || (corner_lo && kb == 0)) {
            const int s0g = kb * 64;
            #pragma unroll
            for (int ct = 0; ct < 4; ++ct)
                #pragma unroll
                for (int r = 0; r < 4; ++r) {
                    int t_g = t0 + myt;
                    int s_g = s0g + 16 * ct + 4 * quad + r;
                    int df = s_g - t_g;
                    if (df >= 1019 && df <= 1023) {
                        const float* ekp = &eks[(df - 1019) * 64];
                        float sacc = 0.f;
                        for (int d = 0; d < 64; ++d)
                            sacc += (float)Qs[myt * 64 + (((d >> 3) ^ (myt & 7)) << 3) + (d & 7)] * ekp[d];
                        S[ct][r] += sacc;
                    } else if (df >= -1023 && df <= -1021) {
                        const float* ekp = &eks[(1029 + df) * 64];
                        const int t2 = myt - 1;
                        float sacc = 0.f;
                        for (int d = 0; d < 64; ++d)
                            sacc += (float)Qs[t2 * 64 + (((d >> 3) ^ (t2 & 7)) << 3) + (d & 7)] * ekp[d];
                        S[ct][r] += sacc;
                    }
                }
        }

        // ----- no-max softmax: P = exp2(S); store Ps (wave-private rows) -----
        #pragma unroll
        for (int ct = 0; ct < 4; ++ct) {
            f16x4 pk_;
            #pragma unroll
            for (int r = 0; r < 4; ++r) {
                float p = exp2f(S[ct][r]);
                Ssum += p;
                pk_[r] = (f16)p;
            }
            int colh = (((2 * ct + (quad >> 1)) ^ (myt & 7)) << 3) + (quad & 1) * 4;
            *(f16x4*)&Ps[myt * 64 + colh] = pk_;
        }
        // NO barrier: Ps rows 16w..16w+15 are written and read by wave w only;
        // compiler's lgkmcnt ordering covers the in-wave write->read dependency.

        // ----- O += P V -----
        #pragma unroll
        for (int ks = 0; ks < 2; ++ks) {
            f16x8 a = *(const f16x8*)&Ps[(16 * w + l15) * 64 + (((ks * 4 + quad) ^ (l15 & 7)) << 3)];
            #pragma unroll
            for (int ct = 0; ct < 4; ++ct) {
                f16x8 bf = *(const f16x8*)&Vs[cb][(16 * ct + l15) * 64 + (((ks * 4 + quad) ^ (l15 & 7)) << 3)];
                O[ct] = __builtin_amdgcn_mfma_f32_16x16x32_f16(a, bf, O[ct], 0, 0, 0);
            }
        }

        // ----- windowed relative-V (reads own wave's Ps rows) -----
        const int s0g = kb * 64;
        if (s0g <= t0 + 67 && s0g + 63 >= t0 - 4) {
            #pragma unroll
            for (int r = 0; r < 4; ++r) {
                int t_loc = 16 * w + 4 * quad + r;
                int t_g = t0 + t_loc;
                int slo = max(s0g, t_g - 4), shi = min(s0g + 63, t_g + 4);
                for (int s = slo; s <= shi; ++s) {
                    int sl = s - s0g;
                    float p = (float)Ps[t_loc * 64 + (((sl >> 3) ^ (t_loc & 7)) << 3) + (sl & 7)];
                    const float* evp = &evs[(s - t_g + 4) * 64];
                    #pragma unroll
                    for (int ct = 0; ct < 4; ++ct)
                        O[ct][r] += p * evp[16 * ct + l15];
                }
            }
        }
    }

    // full row-sum -> normalize in-kernel
    Ssum += __shfl_xor(Ssum, 16);
    Ssum += __shfl_xor(Ssum, 32);
    if (quad == 0) ls[myt] = 1.0f / Ssum;
    __syncthreads();

    #pragma unroll
    for (int r = 0; r < 4; ++r) {
        const int t_loc = 16 * w + 4 * quad + r;
        const float rl = ls[t_loc];
        size_t rowo = ((size_t)(b * T_LEN + t0 + t_loc)) * CCH + h * DH;
        #pragma unroll
        for (int ct = 0; ct < 4; ++ct)
            ctx[rowo + 16 * ct + l15] = (f16)(O[ct][r] * rl);
    }
}

// ---------------------------------------------------------------------------
// Output projection v2: ctx B-frags via register double-buffer (wave-private
// rows), Wo via DMA-staged dbuf LDS. 64(o)x64(t), BK=64. grid(B*16, 8).
// fp32 out [b][o][t].
// ---------------------------------------------------------------------------
__global__ __launch_bounds__(256)
void proj_out(const f16* __restrict__ ctx, const f16* __restrict__ Wo,
              const float* __restrict__ bo, float* __restrict__ out)
{
    const int r0 = blockIdx.x * 64;
    const int o0 = blockIdx.y * 64;
    const int tid = threadIdx.x;
    const int w = tid >> 6, lane = tid & 63;
    const int quad = lane >> 4, l15 = lane & 15;

    __shared__ __align__(16) f16 Ws[2][4096];

    const int srow = tid >> 3;
    const int scol = ((tid & 7) ^ (srow & 7)) << 3;
    const f16* Wg = Wo + (size_t)(o0 + srow) * CCH + scol;

    dma16(Wg, &Ws[0][(size_t)tid * 8]);
    dma16(Wg + (size_t)32 * CCH, &Ws[0][((size_t)tid + 256) * 8]);

    const f16* cp = ctx + (size_t)(r0 + 16 * w + l15) * CCH + quad * 8;
    f16x8 cf[2];
    #pragma unroll
    for (int ks = 0; ks < 2; ++ks)
        cf[ks] = *(const f16x8*)&cp[ks * 32];

    f32x4 acc[4] = {};

    for (int kc = 0; kc < 8; ++kc) {
        __syncthreads();
        if (kc < 7) {
            const int bf = (kc + 1) & 1, c1 = (kc + 1) * 64;
            dma16(Wg + c1, &Ws[bf][(size_t)tid * 8]);
            dma16(Wg + c1 + (size_t)32 * CCH, &Ws[bf][((size_t)tid + 256) * 8]);
        }
        const int nk = ((kc + 1) & 7) * 64;
        f16x8 cn[2];
        #pragma unroll
        for (int ks = 0; ks < 2; ++ks)
            cn[ks] = *(const f16x8*)&cp[nk + ks * 32];

        const int cb = kc & 1;
        #pragma unroll
        for (int ks = 0; ks < 2; ++ks) {
            const int sl = ((ks * 4 + quad) ^ (l15 & 7)) << 3;
            #pragma unroll
            for (int cm = 0; cm < 4; ++cm) {
                f16x8 wf = *(const f16x8*)&Ws[cb][(16 * cm + l15) * 64 + sl];
                acc[cm] = __builtin_amdgcn_mfma_f32_16x16x32_f16(wf, cf[ks], acc[cm], 0, 0, 0);
            }
        }
        cf[0] = cn[0];
        cf[1] = cn[1];
    }

    const int bb = r0 >> 10, tb = r0 & 1023;
    #pragma unroll
    for (int cm = 0; cm < 4; ++cm) {
        float4 bv4 = *(const float4*)&bo[o0 + 16 * cm + 4 * quad];
        float bl[4] = {bv4.x, bv4.y, bv4.z, bv4.w};
        #pragma unroll
        for (int r = 0; r < 4; ++r) {
            size_t row = ((size_t)(bb * CCH + o0 + 16 * cm + 4 * quad + r)) * T_LEN;
            out[row + tb + 16 * w + l15] = acc[cm][r] + bl[r];
        }
    }
}

// ---------------------------------------------------------------------------
extern "C" void kernel_launch(void* const* d_in, const int* in_sizes, int n_in,
                              void* d_out, int out_size, void* d_ws, size_t ws_size,
                              hipStream_t stream)
{
    const float* x_q = (const float*)d_in[0];
    const float* x_k = (const float*)d_in[1];
    const float* x_v = (const float*)d_in[2];
    const float* Wq  = (const float*)d_in[3];
    const float* bq  = (const float*)d_in[4];
    const float* Wk  = (const float*)d_in[5];
    const float* bk  = (const float*)d_in[6];
    const float* Wv  = (const float*)d_in[7];
    const float* bv  = (const float*)d_in[8];
    const float* Wo  = (const float*)d_in[9];
    const float* bo  = (const float*)d_in[10];
    const float* erk = (const float*)d_in[11];
    const float* erv = (const float*)d_in[12];

    const int B = in_sizes[0] / (CCH * T_LEN);
    const size_t te = (size_t)B * CCH * T_LEN;
    const size_t we = (size_t)CCH * CCH;

    f16* p = (f16*)d_ws;
    f16* xTq = p; p += te;
    f16* xTk = p; p += te;
    f16* xTv = p; p += te;
    f16* wqh = p; p += we;
    f16* wkh = p; p += we;
    f16* wvh = p; p += we;
    f16* woh = p; p += we;
    f16* qh  = p; p += te;
    f16* kh  = p; p += te;
    f16* vh  = p; p += te;
    f16* ch  = p; p += te;

    dim3 blk(256);
    prep_kernel<<<dim3(16, 8, 3 * B + 8), blk, 0, stream>>>(
        x_q, x_k, x_v, Wq, Wk, Wv, Wo, xTq, xTk, xTv, wqh, wkh, wvh, woh, B);
    proj_qkv<<<dim3(B * 8, 8, 3), blk, 0, stream>>>(
        xTq, xTk, xTv, wqh, wkh, wvh, bq, bk, bv, qh, kh, vh);
    attn_mfma<<<dim3(T_LEN / 64, NH, B), blk, 0, stream>>>(
        qh, kh, vh, erk, erv, ch);
    proj_out<<<dim3(B * 16, 8), blk, 0, stream>>>(
        ch, woh, bo, (float*)d_out);
}